// Round 12
// baseline (97.591 us; speedup 1.0000x reference)
//
#include <hip/hip_runtime.h>

#define N_NODES 100000
#define N_EDGES 3200000
#define N_FEAT  256
#define N_HID   64

// ---- bin partition geometry ----
#define NBINS     256                       // one bin per CU for bindeg/binacc
#define BIN_W     391                       // ceil(100000/256); last bin has 295 nodes
#define BIN_CAP   13568                     // mean 12500, sigma ~110 -> +9.7 sigma
#define NPART     1000                      // partition chunks (hist & scatter blocks)
#define EPB       3200                      // edges per chunk (1000*3200 = 3.2M exact)
#define I4PB      800                       // int4 groups per chunk
#define NPQ       25000                     // pq blocks (4 nodes each)
#define CPT       4                         // scan: chunks per thread (4*250=1000)

// ---------------------------------------------------------------------------
// Stage 1 (fused): per-chunk LDS histogram of target bins -> hist[blk][bin].
// Block 0 additionally computes W_comb and bias_y.
// ---------------------------------------------------------------------------
__global__ __launch_bounds__(256) void k_histw(
        const int4* __restrict__ col4, int* __restrict__ hist,
        const float* __restrict__ Wg, const float* __restrict__ bg,
        const float* __restrict__ Wc, const float* __restrict__ bc,
        float* __restrict__ wcomb, float* __restrict__ biasy) {
    __shared__ int h[NBINS];
    int tid = threadIdx.x;
    if (blockIdx.x == 0) {
        float s = 0.f;
#pragma unroll
        for (int k = 0; k < N_HID; ++k) s += Wg[tid * N_HID + k] * Wc[k];
        wcomb[tid] = s;
        if (tid == 0) {
            float b = 0.f;
            for (int k = 0; k < N_HID; ++k) b += bg[k] * Wc[k];
            *biasy = b + bc[0];
        }
    }
    h[tid] = 0;
    __syncthreads();
    int i0 = blockIdx.x * I4PB;
    for (int i = i0 + tid; i < i0 + I4PB; i += 256) {
        int4 c = col4[i];
        atomicAdd(&h[c.x / BIN_W], 1);
        atomicAdd(&h[c.y / BIN_W], 1);
        atomicAdd(&h[c.z / BIN_W], 1);
        atomicAdd(&h[c.w / BIN_W], 1);
    }
    __syncthreads();
    hist[blockIdx.x * NBINS + tid] = h[tid];
}

// ---------------------------------------------------------------------------
// Stage 2: parallel scan, one block per bin. Thread t owns chunks [4t,4t+4):
// block scan of 256 partials -> exclusive starts base[blk][bin];
// cursor[bin] = bin total. ~1MB touched, L2-resident.
// ---------------------------------------------------------------------------
__global__ __launch_bounds__(256) void k_scan(const int* __restrict__ hist,
                                              int* __restrict__ base,
                                              int* __restrict__ cursor) {
    __shared__ int ps[256];
    int b = blockIdx.x, t = threadIdx.x;
    int v[CPT];
    int sum = 0;
    int c0 = t * CPT;
#pragma unroll
    for (int j = 0; j < CPT; ++j) {
        int blk = c0 + j;
        v[j] = (blk < NPART) ? hist[blk * NBINS + b] : 0;
        sum += v[j];
    }
    ps[t] = sum;
    __syncthreads();
#pragma unroll
    for (int d = 1; d < 256; d <<= 1) {
        int x = (t >= d) ? ps[t - d] : 0;
        __syncthreads();
        ps[t] += x;
        __syncthreads();
    }
    int run = ps[t] - sum;   // exclusive prefix of this thread's group
#pragma unroll
    for (int j = 0; j < CPT; ++j) {
        int blk = c0 + j;
        if (blk < NPART) { base[blk * NBINS + b] = run; run += v[j]; }
    }
    if (t == 255) cursor[b] = ps[255];
}

// ---------------------------------------------------------------------------
// Stage 3 (fused heterogeneous), pq blocks FIRST so the HBM-bound streaming
// starts at cycle 0 and the latency-bound scatter blocks backfill:
//   blocks [0, NPQ)          : wave-per-node dual dot product (HBM-bound)
//   blocks [NPQ, NPQ+NPART)  : LDS-staged scatter to exact positions, ZERO
//                              global atomics (17.8 KB LDS -> full occupancy)
// packed word = (local_target << 17) | src   (src < 2^17, local < 391)
// ---------------------------------------------------------------------------
__global__ __launch_bounds__(256) void k_scatpq(
        const int4* __restrict__ row4, const int4* __restrict__ col4,
        const int* __restrict__ hist, const int* __restrict__ base,
        unsigned int* __restrict__ grouped,
        const float* __restrict__ x, const float* __restrict__ West,
        const float* __restrict__ wcomb, float2* __restrict__ pq) {
    __shared__ int cnts[NBINS];
    __shared__ int lstart[NBINS];
    __shared__ int lcount[NBINS];
    __shared__ int gbase[NBINS];
    __shared__ int scan[NBINS];
    __shared__ unsigned int stage[EPB];          // 12.8 KB (total 17.8 KB)
    int tid = threadIdx.x;

    if (blockIdx.x < NPQ) {
        // ---------------- pq branch ----------------
        int node = ((int)blockIdx.x << 2) + (tid >> 6);
        int lane = tid & 63;
        if (node >= N_NODES) return;
        float4 v  = ((const float4*)(x + (size_t)node * N_FEAT))[lane];
        float4 we = ((const float4*)West)[lane];
        float4 wc = ((const float4*)wcomb)[lane];
        float ps = v.x * we.x + v.y * we.y + v.z * we.z + v.w * we.w;
        float qs = v.x * wc.x + v.y * wc.y + v.z * wc.z + v.w * wc.w;
#pragma unroll
        for (int off = 32; off > 0; off >>= 1) {
            ps += __shfl_down(ps, off);
            qs += __shfl_down(qs, off);
        }
        if (lane == 0) pq[node] = make_float2(qs, ps);  // .x = y-path, .y = s-path
        return;
    }

    // ---------------- scatter branch ----------------
    const int blk = (int)blockIdx.x - NPQ;
    int cnt = hist[blk * NBINS + tid];
    cnts[tid]   = cnt;
    gbase[tid]  = base[blk * NBINS + tid];
    scan[tid]   = cnt;
    lcount[tid] = 0;
    __syncthreads();
#pragma unroll
    for (int d = 1; d < 256; d <<= 1) {
        int t = (tid >= d) ? scan[tid - d] : 0;
        __syncthreads();
        scan[tid] += t;
        __syncthreads();
    }
    lstart[tid] = scan[tid] - cnt;
    __syncthreads();

    int i0 = blk * I4PB;
    for (int i = i0 + tid; i < i0 + I4PB; i += 256) {
        int4 c = col4[i];
        int4 r = row4[i];
        int b0 = c.x / BIN_W; int s0 = lstart[b0] + atomicAdd(&lcount[b0], 1);
        stage[s0] = ((unsigned)(c.x - b0 * BIN_W) << 17) | (unsigned)r.x;
        int b1 = c.y / BIN_W; int s1 = lstart[b1] + atomicAdd(&lcount[b1], 1);
        stage[s1] = ((unsigned)(c.y - b1 * BIN_W) << 17) | (unsigned)r.y;
        int b2 = c.z / BIN_W; int s2 = lstart[b2] + atomicAdd(&lcount[b2], 1);
        stage[s2] = ((unsigned)(c.z - b2 * BIN_W) << 17) | (unsigned)r.z;
        int b3 = c.w / BIN_W; int s3 = lstart[b3] + atomicAdd(&lcount[b3], 1);
        stage[s3] = ((unsigned)(c.w - b3 * BIN_W) << 17) | (unsigned)r.w;
    }
    __syncthreads();

    // burst copy, one wave per bin (avg run ~12.5)
    int wid = tid >> 6, lane = tid & 63;
    for (int b = wid; b < NBINS; b += 4) {
        int s = lstart[b], len = cnts[b], gb = gbase[b];
        unsigned int* dst = grouped + (size_t)b * BIN_CAP + gb;
        for (int off = lane; off < len; off += 64)
            if (gb + off < BIN_CAP) dst[off] = stage[s + off];
    }
}

// ---------------------------------------------------------------------------
// Per-bin degree histogram (LDS) -> dinv, table = dinv * pq.
// 1024 threads, uint4 4-edge loads for MLP depth.
// ---------------------------------------------------------------------------
__global__ __launch_bounds__(1024) void k_bindeg(const int* __restrict__ cursor,
                                                 const unsigned int* __restrict__ grouped,
                                                 const float2* __restrict__ pq,
                                                 float* __restrict__ dinv,
                                                 float2* __restrict__ table) {
    __shared__ int dh[BIN_W];
    int b = blockIdx.x, tid = threadIdx.x;
    for (int i = tid; i < BIN_W; i += 1024) dh[i] = 0;
    __syncthreads();
    int cnt = cursor[b];
    if (cnt > BIN_CAP) cnt = BIN_CAP;
    const unsigned int* g = grouped + (size_t)b * BIN_CAP;
    const uint4* g4 = (const uint4*)g;
    int n4 = cnt >> 2;
    for (int i = tid; i < n4; i += 1024) {
        uint4 v = g4[i];
        atomicAdd(&dh[v.x >> 17], 1);
        atomicAdd(&dh[v.y >> 17], 1);
        atomicAdd(&dh[v.z >> 17], 1);
        atomicAdd(&dh[v.w >> 17], 1);
    }
    for (int i = (cnt & ~3) + tid; i < cnt; i += 1024)   // tail (<=3)
        atomicAdd(&dh[g[i] >> 17], 1);
    __syncthreads();
    for (int l = tid; l < BIN_W; l += 1024) {
        int node = b * BIN_W + l;
        if (node < N_NODES) {
            float di = rsqrtf((float)(dh[l] + 1));   // +1 self-loop
            dinv[node] = di;
            float2 v = pq[node];
            table[node] = make_float2(di * v.x, di * v.y);
        }
    }
}

// ---------------------------------------------------------------------------
// Per-bin accumulate: SoA LDS tiles (all 32 banks), uint4 4-edge loads
// (4 in-flight L2 gathers per thread), ds_add_f32 on-CU atomics,
// self-loop pre-added, finalize fused.
// ---------------------------------------------------------------------------
__global__ __launch_bounds__(1024) void k_binacc(const int* __restrict__ cursor,
                                                 const unsigned int* __restrict__ grouped,
                                                 const float2* __restrict__ table,
                                                 const float* __restrict__ dinv,
                                                 const float* __restrict__ biasy,
                                                 const float* __restrict__ best,
                                                 float* __restrict__ out) {
    __shared__ float tx[BIN_W];
    __shared__ float ty[BIN_W];
    int b = blockIdx.x, tid = threadIdx.x;
    for (int l = tid; l < BIN_W; l += 1024) {
        int node = b * BIN_W + l;
        float2 t = (node < N_NODES) ? table[node] : make_float2(0.f, 0.f);
        tx[l] = t.x;
        ty[l] = t.y;
    }
    __syncthreads();
    int cnt = cursor[b];
    if (cnt > BIN_CAP) cnt = BIN_CAP;
    const unsigned int* g = grouped + (size_t)b * BIN_CAP;
    const uint4* g4 = (const uint4*)g;
    int n4 = cnt >> 2;
    for (int i = tid; i < n4; i += 1024) {
        uint4 v = g4[i];
        float2 t0 = table[v.x & 0x1FFFFu];
        float2 t1 = table[v.y & 0x1FFFFu];
        float2 t2 = table[v.z & 0x1FFFFu];
        float2 t3 = table[v.w & 0x1FFFFu];
        atomicAdd(&tx[v.x >> 17], t0.x);
        atomicAdd(&ty[v.x >> 17], t0.y);
        atomicAdd(&tx[v.y >> 17], t1.x);
        atomicAdd(&ty[v.y >> 17], t1.y);
        atomicAdd(&tx[v.z >> 17], t2.x);
        atomicAdd(&ty[v.z >> 17], t2.y);
        atomicAdd(&tx[v.w >> 17], t3.x);
        atomicAdd(&ty[v.w >> 17], t3.y);
    }
    for (int i = (cnt & ~3) + tid; i < cnt; i += 1024) {  // tail (<=3)
        unsigned int v = g[i];
        float2 t = table[v & 0x1FFFFu];
        atomicAdd(&tx[v >> 17], t.x);
        atomicAdd(&ty[v >> 17], t.y);
    }
    __syncthreads();
    float by = biasy[0], bs = best[0];
    for (int l = tid; l < BIN_W; l += 1024) {
        int node = b * BIN_W + l;
        if (node < N_NODES) {
            float di = dinv[node];
            out[node]           = di * tx[l] + by;
            out[N_NODES + node] = di * ty[l] + bs;
        }
    }
}

// ===========================================================================
// Fallback pipeline (proven ~500us) used only if ws_size is too small.
// ===========================================================================
__global__ void k_wcomb_fb(const float* __restrict__ Wg, const float* __restrict__ bg,
                           const float* __restrict__ Wc, const float* __restrict__ bc,
                           float* __restrict__ wcomb, float* __restrict__ biasy) {
    int f = threadIdx.x;
    float s = 0.f;
#pragma unroll
    for (int k = 0; k < N_HID; ++k) s += Wg[f * N_HID + k] * Wc[k];
    wcomb[f] = s;
    if (f == 0) {
        float b = 0.f;
        for (int k = 0; k < N_HID; ++k) b += bg[k] * Wc[k];
        *biasy = b + bc[0];
    }
}
__global__ __launch_bounds__(256) void k_deg_fb(const int* __restrict__ col,
                                                int* __restrict__ deg) {
    int e = blockIdx.x * blockDim.x + threadIdx.x;
    if (e < N_EDGES) atomicAdd(&deg[col[e]], 1);
}
__global__ __launch_bounds__(256) void k_pqtable_fb(
        const float* __restrict__ x, const float* __restrict__ West,
        const float* __restrict__ wcomb, const int* __restrict__ deg,
        float* __restrict__ dinv, float2* __restrict__ table,
        float2* __restrict__ acc) {
    int node = (blockIdx.x * blockDim.x + threadIdx.x) >> 6;
    int lane = threadIdx.x & 63;
    if (node >= N_NODES) return;
    float4 v  = ((const float4*)(x + (size_t)node * N_FEAT))[lane];
    float4 we = ((const float4*)West)[lane];
    float4 wc = ((const float4*)wcomb)[lane];
    float ps = v.x * we.x + v.y * we.y + v.z * we.z + v.w * we.w;
    float qs = v.x * wc.x + v.y * wc.y + v.z * wc.z + v.w * wc.w;
#pragma unroll
    for (int off = 32; off > 0; off >>= 1) {
        ps += __shfl_down(ps, off);
        qs += __shfl_down(qs, off);
    }
    if (lane == 0) {
        float di = rsqrtf((float)(deg[node] + 1));
        float2 t = make_float2(di * qs, di * ps);
        dinv[node] = di; table[node] = t; acc[node] = t;
    }
}
__global__ __launch_bounds__(256) void k_edge_fb(const int* __restrict__ ei,
                                                 const float2* __restrict__ table,
                                                 float2* __restrict__ acc) {
    int e = blockIdx.x * blockDim.x + threadIdx.x;
    if (e >= N_EDGES) return;
    float2 t = table[ei[e]];
    int c = ei[N_EDGES + e];
    unsafeAtomicAdd(&acc[c].x, t.x);
    unsafeAtomicAdd(&acc[c].y, t.y);
}
__global__ __launch_bounds__(256) void k_fin_fb(
        const float* __restrict__ dinv, const float2* __restrict__ acc,
        const float* __restrict__ biasy, const float* __restrict__ best,
        float* __restrict__ out) {
    int i = blockIdx.x * blockDim.x + threadIdx.x;
    if (i >= N_NODES) return;
    float di = dinv[i];
    float2 a = acc[i];
    out[i]           = di * a.x + biasy[0];
    out[N_NODES + i] = di * a.y + best[0];
}

extern "C" void kernel_launch(void* const* d_in, const int* in_sizes, int n_in,
                              void* d_out, int out_size, void* d_ws, size_t ws_size,
                              hipStream_t stream) {
    const int*   ei   = (const int*)d_in[0];
    const float* x    = (const float*)d_in[1];
    const float* West = (const float*)d_in[2];
    const float* best = (const float*)d_in[3];
    const float* Wg   = (const float*)d_in[4];
    const float* bg   = (const float*)d_in[5];
    const float* Wc   = (const float*)d_in[6];
    const float* bc   = (const float*)d_in[7];
    float* out = (float*)d_out;

    // ---- workspace layout (bytes) ----
    char* ws = (char*)d_ws;
    float*  wcomb = (float*)ws;                       // 256 f          @ 0
    float*  biasy = wcomb + 256;                      // 1 f
    float2* pq    = (float2*)(ws + 2048);             // N f2  (800000 B)
    float2* table = (float2*)(ws + 802048);           // N f2  (800000 B)
    float*  dinv  = (float*)(ws + 1602048);           // N f   (400000 B)
    int*    cursor= (int*)(ws + 2002048);             // NBINS i (1024 B)
    unsigned int* grouped = (unsigned int*)(ws + 2003072);  // NBINS*BIN_CAP u32 (13.9 MB)
    int*    hist  = (int*)(ws + 2003072 + (size_t)NBINS * BIN_CAP * 4);  // NPART*NBINS i
    int*    base  = hist + (size_t)NPART * NBINS;
    size_t need = 2003072 + (size_t)NBINS * BIN_CAP * 4 + (size_t)NPART * NBINS * 8;

    if (ws_size >= need) {
        k_histw<<<NPART, 256, 0, stream>>>((const int4*)(ei + N_EDGES), hist,
                                           Wg, bg, Wc, bc, wcomb, biasy);
        k_scan<<<NBINS, 256, 0, stream>>>(hist, base, cursor);
        k_scatpq<<<NPQ + NPART, 256, 0, stream>>>((const int4*)ei,
                                                  (const int4*)(ei + N_EDGES),
                                                  hist, base, grouped,
                                                  x, West, wcomb, pq);
        k_bindeg<<<NBINS, 1024, 0, stream>>>(cursor, grouped, pq, dinv, table);
        k_binacc<<<NBINS, 1024, 0, stream>>>(cursor, grouped, table, dinv,
                                             biasy, best, out);
    } else {
        // fallback: global-atomic pipeline (needs ~2.4 MB)
        int*    deg  = (int*)(ws + 2048 + 800000 * 2 + 400000);
        float2* acc  = pq;       // reuse
        float2* tbl  = table;
        hipMemsetAsync(deg, 0, N_NODES * sizeof(int), stream);
        k_wcomb_fb<<<1, 256, 0, stream>>>(Wg, bg, Wc, bc, wcomb, biasy);
        k_deg_fb<<<(N_EDGES + 255) / 256, 256, 0, stream>>>(ei + N_EDGES, deg);
        k_pqtable_fb<<<(N_NODES * 64 + 255) / 256, 256, 0, stream>>>(
            x, West, wcomb, deg, dinv, tbl, acc);
        k_edge_fb<<<(N_EDGES + 255) / 256, 256, 0, stream>>>(ei, tbl, acc);
        k_fin_fb<<<(N_NODES + 255) / 256, 256, 0, stream>>>(dinv, acc, biasy, best, out);
    }
}

// Round 13
// 86.271 us; speedup vs baseline: 1.1312x; 1.1312x over previous
//
#include <hip/hip_runtime.h>

#define N_NODES 100000
#define N_EDGES 3200000
#define N_FEAT  256
#define N_HID   64

// ---- bin partition geometry ----
#define NBINS     256                       // one bin per CU for bindeg/binacc
#define BIN_W     391                       // ceil(100000/256); last bin has 295 nodes
#define BIN_CAP   13568                     // mean 12500, sigma ~110 -> +9.7 sigma
#define NPART     1000                      // partition chunks (hist & scatter blocks)
#define EPB       3200                      // edges per chunk (1000*3200 = 3.2M exact)
#define I4PB      800                       // int4 groups per chunk
#define NPQ       25000                     // pq blocks (4 nodes each)
#define CPT       4                         // scan: chunks per thread (4*250=1000)

// ---------------------------------------------------------------------------
// Stage 1 (fused): per-chunk LDS histogram of target bins -> hist[blk][bin].
// Block 0 additionally computes W_comb and bias_y.
// ---------------------------------------------------------------------------
__global__ __launch_bounds__(256) void k_histw(
        const int4* __restrict__ col4, int* __restrict__ hist,
        const float* __restrict__ Wg, const float* __restrict__ bg,
        const float* __restrict__ Wc, const float* __restrict__ bc,
        float* __restrict__ wcomb, float* __restrict__ biasy) {
    __shared__ int h[NBINS];
    int tid = threadIdx.x;
    if (blockIdx.x == 0) {
        float s = 0.f;
#pragma unroll
        for (int k = 0; k < N_HID; ++k) s += Wg[tid * N_HID + k] * Wc[k];
        wcomb[tid] = s;
        if (tid == 0) {
            float b = 0.f;
            for (int k = 0; k < N_HID; ++k) b += bg[k] * Wc[k];
            *biasy = b + bc[0];
        }
    }
    h[tid] = 0;
    __syncthreads();
    int i0 = blockIdx.x * I4PB;
    for (int i = i0 + tid; i < i0 + I4PB; i += 256) {
        int4 c = col4[i];
        atomicAdd(&h[c.x / BIN_W], 1);
        atomicAdd(&h[c.y / BIN_W], 1);
        atomicAdd(&h[c.z / BIN_W], 1);
        atomicAdd(&h[c.w / BIN_W], 1);
    }
    __syncthreads();
    hist[blockIdx.x * NBINS + tid] = h[tid];
}

// ---------------------------------------------------------------------------
// Stage 2: parallel scan, one block per bin. Thread t owns chunks [4t,4t+4):
// block scan of 256 partials -> exclusive starts base[blk][bin];
// cursor[bin] = bin total. ~1MB touched, L2-resident.
// ---------------------------------------------------------------------------
__global__ __launch_bounds__(256) void k_scan(const int* __restrict__ hist,
                                              int* __restrict__ base,
                                              int* __restrict__ cursor) {
    __shared__ int ps[256];
    int b = blockIdx.x, t = threadIdx.x;
    int v[CPT];
    int sum = 0;
    int c0 = t * CPT;
#pragma unroll
    for (int j = 0; j < CPT; ++j) {
        int blk = c0 + j;
        v[j] = (blk < NPART) ? hist[blk * NBINS + b] : 0;
        sum += v[j];
    }
    ps[t] = sum;
    __syncthreads();
#pragma unroll
    for (int d = 1; d < 256; d <<= 1) {
        int x = (t >= d) ? ps[t - d] : 0;
        __syncthreads();
        ps[t] += x;
        __syncthreads();
    }
    int run = ps[t] - sum;   // exclusive prefix of this thread's group
#pragma unroll
    for (int j = 0; j < CPT; ++j) {
        int blk = c0 + j;
        if (blk < NPART) { base[blk * NBINS + b] = run; run += v[j]; }
    }
    if (t == 255) cursor[b] = ps[255];
}

// ---------------------------------------------------------------------------
// Stage 3 (fused heterogeneous). BLOCK ORDER MATTERS: scatter blocks FIRST
// (long-pole, 1000 blocks) so they start at cycle 0; short pq blocks backfill
// the remaining wave slots and stream HBM concurrently. (r12 proved the
// reverse order serializes: pq drains before any scatter block starts.)
//   blocks [0, NPART)        : LDS-staged scatter, ZERO global atomics
//   blocks [NPART,NPART+NPQ) : wave-per-node dual dot product (HBM-bound)
// packed word = (local_target << 17) | src   (src < 2^17, local < 391)
// ---------------------------------------------------------------------------
__global__ __launch_bounds__(256) void k_scatpq(
        const int4* __restrict__ row4, const int4* __restrict__ col4,
        const int* __restrict__ hist, const int* __restrict__ base,
        unsigned int* __restrict__ grouped,
        const float* __restrict__ x, const float* __restrict__ West,
        const float* __restrict__ wcomb, float2* __restrict__ pq) {
    __shared__ int cnts[NBINS];
    __shared__ int lstart[NBINS];
    __shared__ int lcount[NBINS];
    __shared__ int gbase[NBINS];
    __shared__ int scan[NBINS];
    __shared__ unsigned int stage[EPB];          // 12.8 KB (total 17.8 KB)
    int tid = threadIdx.x;

    if (blockIdx.x >= NPART) {
        // ---------------- pq branch ----------------
        int node = (((int)blockIdx.x - NPART) << 2) + (tid >> 6);
        int lane = tid & 63;
        if (node >= N_NODES) return;
        float4 v  = ((const float4*)(x + (size_t)node * N_FEAT))[lane];
        float4 we = ((const float4*)West)[lane];
        float4 wc = ((const float4*)wcomb)[lane];
        float ps = v.x * we.x + v.y * we.y + v.z * we.z + v.w * we.w;
        float qs = v.x * wc.x + v.y * wc.y + v.z * wc.z + v.w * wc.w;
#pragma unroll
        for (int off = 32; off > 0; off >>= 1) {
            ps += __shfl_down(ps, off);
            qs += __shfl_down(qs, off);
        }
        if (lane == 0) pq[node] = make_float2(qs, ps);  // .x = y-path, .y = s-path
        return;
    }

    // ---------------- scatter branch ----------------
    int cnt = hist[blockIdx.x * NBINS + tid];
    cnts[tid]   = cnt;
    gbase[tid]  = base[blockIdx.x * NBINS + tid];
    scan[tid]   = cnt;
    lcount[tid] = 0;
    __syncthreads();
#pragma unroll
    for (int d = 1; d < 256; d <<= 1) {
        int t = (tid >= d) ? scan[tid - d] : 0;
        __syncthreads();
        scan[tid] += t;
        __syncthreads();
    }
    lstart[tid] = scan[tid] - cnt;
    __syncthreads();

    int i0 = blockIdx.x * I4PB;
    for (int i = i0 + tid; i < i0 + I4PB; i += 256) {
        int4 c = col4[i];
        int4 r = row4[i];
        int b0 = c.x / BIN_W; int s0 = lstart[b0] + atomicAdd(&lcount[b0], 1);
        stage[s0] = ((unsigned)(c.x - b0 * BIN_W) << 17) | (unsigned)r.x;
        int b1 = c.y / BIN_W; int s1 = lstart[b1] + atomicAdd(&lcount[b1], 1);
        stage[s1] = ((unsigned)(c.y - b1 * BIN_W) << 17) | (unsigned)r.y;
        int b2 = c.z / BIN_W; int s2 = lstart[b2] + atomicAdd(&lcount[b2], 1);
        stage[s2] = ((unsigned)(c.z - b2 * BIN_W) << 17) | (unsigned)r.z;
        int b3 = c.w / BIN_W; int s3 = lstart[b3] + atomicAdd(&lcount[b3], 1);
        stage[s3] = ((unsigned)(c.w - b3 * BIN_W) << 17) | (unsigned)r.w;
    }
    __syncthreads();

    // burst copy, one wave per bin (avg run ~12.5)
    int wid = tid >> 6, lane = tid & 63;
    for (int b = wid; b < NBINS; b += 4) {
        int s = lstart[b], len = cnts[b], gb = gbase[b];
        unsigned int* dst = grouped + (size_t)b * BIN_CAP + gb;
        for (int off = lane; off < len; off += 64)
            if (gb + off < BIN_CAP) dst[off] = stage[s + off];
    }
}

// ---------------------------------------------------------------------------
// Per-bin degree histogram (LDS) -> dinv, table = dinv * pq.
// 1024 threads, uint4 4-edge loads for MLP depth.
// ---------------------------------------------------------------------------
__global__ __launch_bounds__(1024) void k_bindeg(const int* __restrict__ cursor,
                                                 const unsigned int* __restrict__ grouped,
                                                 const float2* __restrict__ pq,
                                                 float* __restrict__ dinv,
                                                 float2* __restrict__ table) {
    __shared__ int dh[BIN_W];
    int b = blockIdx.x, tid = threadIdx.x;
    for (int i = tid; i < BIN_W; i += 1024) dh[i] = 0;
    __syncthreads();
    int cnt = cursor[b];
    if (cnt > BIN_CAP) cnt = BIN_CAP;
    const unsigned int* g = grouped + (size_t)b * BIN_CAP;
    const uint4* g4 = (const uint4*)g;
    int n4 = cnt >> 2;
    for (int i = tid; i < n4; i += 1024) {
        uint4 v = g4[i];
        atomicAdd(&dh[v.x >> 17], 1);
        atomicAdd(&dh[v.y >> 17], 1);
        atomicAdd(&dh[v.z >> 17], 1);
        atomicAdd(&dh[v.w >> 17], 1);
    }
    for (int i = (cnt & ~3) + tid; i < cnt; i += 1024)   // tail (<=3)
        atomicAdd(&dh[g[i] >> 17], 1);
    __syncthreads();
    for (int l = tid; l < BIN_W; l += 1024) {
        int node = b * BIN_W + l;
        if (node < N_NODES) {
            float di = rsqrtf((float)(dh[l] + 1));   // +1 self-loop
            dinv[node] = di;
            float2 v = pq[node];
            table[node] = make_float2(di * v.x, di * v.y);
        }
    }
}

// ---------------------------------------------------------------------------
// Per-bin accumulate: SoA LDS tiles (all 32 banks), uint4 4-edge loads
// (4 in-flight L2 gathers per thread), ds_add_f32 on-CU atomics,
// self-loop pre-added, finalize fused.
// ---------------------------------------------------------------------------
__global__ __launch_bounds__(1024) void k_binacc(const int* __restrict__ cursor,
                                                 const unsigned int* __restrict__ grouped,
                                                 const float2* __restrict__ table,
                                                 const float* __restrict__ dinv,
                                                 const float* __restrict__ biasy,
                                                 const float* __restrict__ best,
                                                 float* __restrict__ out) {
    __shared__ float tx[BIN_W];
    __shared__ float ty[BIN_W];
    int b = blockIdx.x, tid = threadIdx.x;
    for (int l = tid; l < BIN_W; l += 1024) {
        int node = b * BIN_W + l;
        float2 t = (node < N_NODES) ? table[node] : make_float2(0.f, 0.f);
        tx[l] = t.x;
        ty[l] = t.y;
    }
    __syncthreads();
    int cnt = cursor[b];
    if (cnt > BIN_CAP) cnt = BIN_CAP;
    const unsigned int* g = grouped + (size_t)b * BIN_CAP;
    const uint4* g4 = (const uint4*)g;
    int n4 = cnt >> 2;
    for (int i = tid; i < n4; i += 1024) {
        uint4 v = g4[i];
        float2 t0 = table[v.x & 0x1FFFFu];
        float2 t1 = table[v.y & 0x1FFFFu];
        float2 t2 = table[v.z & 0x1FFFFu];
        float2 t3 = table[v.w & 0x1FFFFu];
        atomicAdd(&tx[v.x >> 17], t0.x);
        atomicAdd(&ty[v.x >> 17], t0.y);
        atomicAdd(&tx[v.y >> 17], t1.x);
        atomicAdd(&ty[v.y >> 17], t1.y);
        atomicAdd(&tx[v.z >> 17], t2.x);
        atomicAdd(&ty[v.z >> 17], t2.y);
        atomicAdd(&tx[v.w >> 17], t3.x);
        atomicAdd(&ty[v.w >> 17], t3.y);
    }
    for (int i = (cnt & ~3) + tid; i < cnt; i += 1024) {  // tail (<=3)
        unsigned int v = g[i];
        float2 t = table[v & 0x1FFFFu];
        atomicAdd(&tx[v >> 17], t.x);
        atomicAdd(&ty[v >> 17], t.y);
    }
    __syncthreads();
    float by = biasy[0], bs = best[0];
    for (int l = tid; l < BIN_W; l += 1024) {
        int node = b * BIN_W + l;
        if (node < N_NODES) {
            float di = dinv[node];
            out[node]           = di * tx[l] + by;
            out[N_NODES + node] = di * ty[l] + bs;
        }
    }
}

// ===========================================================================
// Fallback pipeline (proven ~500us) used only if ws_size is too small.
// ===========================================================================
__global__ void k_wcomb_fb(const float* __restrict__ Wg, const float* __restrict__ bg,
                           const float* __restrict__ Wc, const float* __restrict__ bc,
                           float* __restrict__ wcomb, float* __restrict__ biasy) {
    int f = threadIdx.x;
    float s = 0.f;
#pragma unroll
    for (int k = 0; k < N_HID; ++k) s += Wg[f * N_HID + k] * Wc[k];
    wcomb[f] = s;
    if (f == 0) {
        float b = 0.f;
        for (int k = 0; k < N_HID; ++k) b += bg[k] * Wc[k];
        *biasy = b + bc[0];
    }
}
__global__ __launch_bounds__(256) void k_deg_fb(const int* __restrict__ col,
                                                int* __restrict__ deg) {
    int e = blockIdx.x * blockDim.x + threadIdx.x;
    if (e < N_EDGES) atomicAdd(&deg[col[e]], 1);
}
__global__ __launch_bounds__(256) void k_pqtable_fb(
        const float* __restrict__ x, const float* __restrict__ West,
        const float* __restrict__ wcomb, const int* __restrict__ deg,
        float* __restrict__ dinv, float2* __restrict__ table,
        float2* __restrict__ acc) {
    int node = (blockIdx.x * blockDim.x + threadIdx.x) >> 6;
    int lane = threadIdx.x & 63;
    if (node >= N_NODES) return;
    float4 v  = ((const float4*)(x + (size_t)node * N_FEAT))[lane];
    float4 we = ((const float4*)West)[lane];
    float4 wc = ((const float4*)wcomb)[lane];
    float ps = v.x * we.x + v.y * we.y + v.z * we.z + v.w * we.w;
    float qs = v.x * wc.x + v.y * wc.y + v.z * wc.z + v.w * wc.w;
#pragma unroll
    for (int off = 32; off > 0; off >>= 1) {
        ps += __shfl_down(ps, off);
        qs += __shfl_down(qs, off);
    }
    if (lane == 0) {
        float di = rsqrtf((float)(deg[node] + 1));
        float2 t = make_float2(di * qs, di * ps);
        dinv[node] = di; table[node] = t; acc[node] = t;
    }
}
__global__ __launch_bounds__(256) void k_edge_fb(const int* __restrict__ ei,
                                                 const float2* __restrict__ table,
                                                 float2* __restrict__ acc) {
    int e = blockIdx.x * blockDim.x + threadIdx.x;
    if (e >= N_EDGES) return;
    float2 t = table[ei[e]];
    int c = ei[N_EDGES + e];
    unsafeAtomicAdd(&acc[c].x, t.x);
    unsafeAtomicAdd(&acc[c].y, t.y);
}
__global__ __launch_bounds__(256) void k_fin_fb(
        const float* __restrict__ dinv, const float2* __restrict__ acc,
        const float* __restrict__ biasy, const float* __restrict__ best,
        float* __restrict__ out) {
    int i = blockIdx.x * blockDim.x + threadIdx.x;
    if (i >= N_NODES) return;
    float di = dinv[i];
    float2 a = acc[i];
    out[i]           = di * a.x + biasy[0];
    out[N_NODES + i] = di * a.y + best[0];
}

extern "C" void kernel_launch(void* const* d_in, const int* in_sizes, int n_in,
                              void* d_out, int out_size, void* d_ws, size_t ws_size,
                              hipStream_t stream) {
    const int*   ei   = (const int*)d_in[0];
    const float* x    = (const float*)d_in[1];
    const float* West = (const float*)d_in[2];
    const float* best = (const float*)d_in[3];
    const float* Wg   = (const float*)d_in[4];
    const float* bg   = (const float*)d_in[5];
    const float* Wc   = (const float*)d_in[6];
    const float* bc   = (const float*)d_in[7];
    float* out = (float*)d_out;

    // ---- workspace layout (bytes) ----
    char* ws = (char*)d_ws;
    float*  wcomb = (float*)ws;                       // 256 f          @ 0
    float*  biasy = wcomb + 256;                      // 1 f
    float2* pq    = (float2*)(ws + 2048);             // N f2  (800000 B)
    float2* table = (float2*)(ws + 802048);           // N f2  (800000 B)
    float*  dinv  = (float*)(ws + 1602048);           // N f   (400000 B)
    int*    cursor= (int*)(ws + 2002048);             // NBINS i (1024 B)
    unsigned int* grouped = (unsigned int*)(ws + 2003072);  // NBINS*BIN_CAP u32 (13.9 MB)
    int*    hist  = (int*)(ws + 2003072 + (size_t)NBINS * BIN_CAP * 4);  // NPART*NBINS i
    int*    base  = hist + (size_t)NPART * NBINS;
    size_t need = 2003072 + (size_t)NBINS * BIN_CAP * 4 + (size_t)NPART * NBINS * 8;

    if (ws_size >= need) {
        k_histw<<<NPART, 256, 0, stream>>>((const int4*)(ei + N_EDGES), hist,
                                           Wg, bg, Wc, bc, wcomb, biasy);
        k_scan<<<NBINS, 256, 0, stream>>>(hist, base, cursor);
        k_scatpq<<<NPART + NPQ, 256, 0, stream>>>((const int4*)ei,
                                                  (const int4*)(ei + N_EDGES),
                                                  hist, base, grouped,
                                                  x, West, wcomb, pq);
        k_bindeg<<<NBINS, 1024, 0, stream>>>(cursor, grouped, pq, dinv, table);
        k_binacc<<<NBINS, 1024, 0, stream>>>(cursor, grouped, table, dinv,
                                             biasy, best, out);
    } else {
        // fallback: global-atomic pipeline (needs ~2.4 MB)
        int*    deg  = (int*)(ws + 2048 + 800000 * 2 + 400000);
        float2* acc  = pq;       // reuse
        float2* tbl  = table;
        hipMemsetAsync(deg, 0, N_NODES * sizeof(int), stream);
        k_wcomb_fb<<<1, 256, 0, stream>>>(Wg, bg, Wc, bc, wcomb, biasy);
        k_deg_fb<<<(N_EDGES + 255) / 256, 256, 0, stream>>>(ei + N_EDGES, deg);
        k_pqtable_fb<<<(N_NODES * 64 + 255) / 256, 256, 0, stream>>>(
            x, West, wcomb, deg, dinv, tbl, acc);
        k_edge_fb<<<(N_EDGES + 255) / 256, 256, 0, stream>>>(ei, tbl, acc);
        k_fin_fb<<<(N_NODES + 255) / 256, 256, 0, stream>>>(dinv, acc, biasy, best, out);
    }
}